// Round 1
// 1645.456 us; speedup vs baseline: 1.0317x; 1.0317x over previous
//
#include <hip/hip_runtime.h>
#include <hip/hip_bf16.h>
#include <math.h>

typedef __bf16 bf16x8 __attribute__((ext_vector_type(8)));
typedef __bf16 bf16x4 __attribute__((ext_vector_type(4)));
typedef float f32x4 __attribute__((ext_vector_type(4)));

typedef __attribute__((address_space(1))) void GV;
typedef __attribute__((address_space(3))) void LV;

// ---------------------------------------------------------------------------
// transpose_cvt<OSTRIDE, EBLOCK>: per-expert [R=2048][C=2048] fp32 -> bf16 ^T
//   EBLOCK=true : out[e][c][r]                 OSTRIDE=2048   (w1t for GEMM1)
//   EBLOCK=false: out[c*OSTRIDE + e*2048 + r]  OSTRIDE=8192   (w2t for GEMM2)
// ---------------------------------------------------------------------------
template <int OSTRIDE, bool EBLOCK>
__global__ __launch_bounds__(256) void transpose_cvt(const float* __restrict__ in,
                                                     __bf16* __restrict__ out) {
  __shared__ float tile[32][33];
  const int e = blockIdx.z;
  const size_t ibase = (size_t)e * 2048 * 2048;
  const size_t obase = EBLOCK ? (size_t)e * 2048 * 2048 : (size_t)e * 2048;
  int c0 = blockIdx.x * 32, r0 = blockIdx.y * 32;
  int tx = threadIdx.x & 31, ty = threadIdx.x >> 5;
#pragma unroll
  for (int i = 0; i < 32; i += 8)
    tile[ty + i][tx] = in[ibase + (size_t)(r0 + ty + i) * 2048 + c0 + tx];
  __syncthreads();
#pragma unroll
  for (int i = 0; i < 32; i += 8)
    out[obase + (size_t)(c0 + ty + i) * OSTRIDE + r0 + tx] = (__bf16)tile[tx][ty + i];
}

// ---------------------------------------------------------------------------
// router_fused: logits -> softmax(fp32) -> top-2 -> renorm -> dense combine
// [N][4] + pair-id + bucket histogram, FUSED with fp32->bf16 conversion of
// the token row (written in TOKEN order; GEMM1 gathers rows via perm).
// Block = 256 thr (4 waves), 16 tokens/block, gate weights staged in LDS.
// ---------------------------------------------------------------------------
__global__ __launch_bounds__(256) void router_fused(const float4* __restrict__ hs4,
                                                    const float4* __restrict__ gw4,
                                                    bf16x4* __restrict__ xb,
                                                    float* __restrict__ comb,
                                                    int* __restrict__ pairid,
                                                    int* __restrict__ cnt) {
  __shared__ float4 gwS[4 * 512];  // 32 KiB: gw[e][d] as float4
  const int tid = threadIdx.x;
  for (int j = tid; j < 2048; j += 256) gwS[j] = gw4[j];
  __syncthreads();

  const int lane = tid & 63;
  const int wv = tid >> 6;
  const int n0 = blockIdx.x * 16;

  for (int t = wv; t < 16; t += 4) {
    const int n = n0 + t;
    const float4* xr = hs4 + (size_t)n * 512;
    bf16x4* dst = xb + (size_t)n * 512;
    float s0 = 0.f, s1 = 0.f, s2 = 0.f, s3 = 0.f;
#pragma unroll
    for (int i = 0; i < 8; ++i) {
      int j = i * 64 + lane;
      float4 v = xr[j];
      float4 g0 = gwS[j], g1 = gwS[512 + j], g2 = gwS[1024 + j], g3 = gwS[1536 + j];
      s0 += v.x * g0.x + v.y * g0.y + v.z * g0.z + v.w * g0.w;
      s1 += v.x * g1.x + v.y * g1.y + v.z * g1.z + v.w * g1.w;
      s2 += v.x * g2.x + v.y * g2.y + v.z * g2.z + v.w * g2.w;
      s3 += v.x * g3.x + v.y * g3.y + v.z * g3.z + v.w * g3.w;
      bf16x4 o;
      o.x = (__bf16)v.x; o.y = (__bf16)v.y; o.z = (__bf16)v.z; o.w = (__bf16)v.w;
      dst[j] = o;
    }
#pragma unroll
    for (int off = 32; off > 0; off >>= 1) {
      s0 += __shfl_down(s0, off);
      s1 += __shfl_down(s1, off);
      s2 += __shfl_down(s2, off);
      s3 += __shfl_down(s3, off);
    }
    if (lane == 0) {
      float l[4] = {s0, s1, s2, s3};
      float m = fmaxf(fmaxf(l[0], l[1]), fmaxf(l[2], l[3]));
      float p[4], sum = 0.f;
#pragma unroll
      for (int e = 0; e < 4; ++e) { p[e] = expf(l[e] - m); sum += p[e]; }
#pragma unroll
      for (int e = 0; e < 4; ++e) p[e] /= sum;
      int i1 = 0;
#pragma unroll
      for (int e = 1; e < 4; ++e) if (p[e] > p[i1]) i1 = e;
      int i2 = -1;
#pragma unroll
      for (int e = 0; e < 4; ++e) {
        if (e == i1) continue;
        if (i2 < 0 || p[e] > p[i2]) i2 = e;
      }
      float ws = p[i1] + p[i2];
#pragma unroll
      for (int e = 0; e < 4; ++e)
        comb[(size_t)n * 4 + e] = (e == i1 || e == i2) ? p[e] / ws : 0.f;
      int a = min(i1, i2), b = max(i1, i2);
      int pid = (a == 0) ? (b - 1) : ((a == 1) ? (1 + b) : (2 + b));
      pairid[n] = pid;
      atomicAdd(&cnt[pid], 1);
    }
  }
}

// exclusive scan over 6 bucket counts (1 thread)
__global__ void scan6(const int* __restrict__ cnt, int* __restrict__ off) {
  int o = 0;
  for (int i = 0; i < 6; ++i) { off[i] = o; o += cnt[i]; }
}

// assign sorted positions; gather combine weights + pair bitmask into sorted order
__global__ __launch_bounds__(256) void assign_kernel(const int* __restrict__ pairid,
                                                     const float4* __restrict__ comb4,
                                                     const int* __restrict__ off,
                                                     int* __restrict__ cur,
                                                     int* __restrict__ perm,
                                                     float4* __restrict__ comb_s,
                                                     int* __restrict__ pm_s) {
  int n = blockIdx.x * 256 + threadIdx.x;
  int pid = pairid[n];
  int pos = off[pid] + atomicAdd(&cur[pid], 1);
  perm[pos] = n;
  comb_s[pos] = comb4[n];
  // pair -> expert bitmask: (0,1)(0,2)(0,3)(1,2)(1,3)(2,3)
  const int lut[6] = {3, 5, 9, 6, 10, 12};
  pm_s[pos] = lut[pid];
}

// per-128-row-tile active-expert mask (OR of token pair-masks)
__global__ void tile_mask_kernel(const int* __restrict__ pm_s, int* __restrict__ tmask) {
  int t = threadIdx.x;  // 128 tiles, 1 block of 128 threads
  int m = 0;
  for (int i = 0; i < 128; ++i) m |= pm_s[t * 128 + i];
  tmask[t] = m;
}

// ---------------------------------------------------------------------------
// gemm_bt<MODE>: C = A[M,K] @ Bt[Nout,K]^T, 128x128 tile, BK=32,
// mfma_f32_16x16x32_bf16, global_load_lds width-16 staging (m97 structure).
// MODE 0: GEMM1 K=2048, Nout=8192. A = token-order xb, rows gathered via
//         permc (global src of global_load_lds is per-lane). Block exits if
//         its expert (bx>>4) inactive; epilogue +b1, gelu, *combine.
// MODE 1: GEMM2 K=8192, Nout=2048: K-loop visits only active experts' ranges;
//         epilogue + sum_e comb*b2, scatter rows via perm.
// ---------------------------------------------------------------------------
template <int MODE>
__global__ __launch_bounds__(256) void gemm_bt(const __bf16* __restrict__ A,
                                               const __bf16* __restrict__ Bt,
                                               const float* __restrict__ bias,
                                               const float* __restrict__ cc,
                                               const int* __restrict__ tmask,
                                               const int* __restrict__ permc,
                                               void* __restrict__ outp) {
  constexpr int K = (MODE == 0) ? 2048 : 8192;
  __shared__ __bf16 ldsA[128 * 32];
  __shared__ __bf16 ldsB[128 * 32];

  const int tid = threadIdx.x;
  const int lane = tid & 63;
  const int wv = tid >> 6;
  const int bx = blockIdx.x, by = blockIdx.y;

  const int tm = tmask[by];
  if (MODE == 0) {
    if (!(tm & (1 << (bx >> 4)))) return;  // expert inactive for this row-tile
  }

  const int lrow = lane & 15;   // A-row / B-col within 16x16 tile
  const int quad = lane >> 4;   // k-group: k = quad*8 + j
  const int mbase = (wv >> 1) * 64;
  const int nbase = (wv & 1) * 64;

  // hoisted per-thread staging bases; MODE 0 gathers token rows through permc
  size_t aoff[2], boff[2];
#pragma unroll
  for (int t = 0; t < 2; ++t) {
    int g = t * 256 + wv * 64 + lane;  // 16B-chunk id, 0..511
    int row = g >> 2, kc = g & 3;
    int arow = by * 128 + row;
    if (MODE == 0) arow = permc[arow];
    aoff[t] = (size_t)arow * K + kc * 8;
    boff[t] = (size_t)(bx * 128 + row) * K + kc * 8;
  }

  f32x4 acc[4][4] = {};

  auto k_step = [&](int kb) {
    __syncthreads();  // protect LDS from previous iteration's readers
#pragma unroll
    for (int t = 0; t < 2; ++t) {
      const __bf16* ga = A + aoff[t] + (size_t)kb * 32;
      const __bf16* gb = Bt + boff[t] + (size_t)kb * 32;
      int loff = t * 2048 + wv * 512;  // wave-uniform LDS base; HW adds lane*16B
      __builtin_amdgcn_global_load_lds((GV*)ga, (LV*)&ldsA[loff], 16, 0, 0);
      __builtin_amdgcn_global_load_lds((GV*)gb, (LV*)&ldsB[loff], 16, 0, 0);
    }
    __syncthreads();

    bf16x8 af[4], bfr[4];
#pragma unroll
    for (int i = 0; i < 4; ++i)
      af[i] = *(const bf16x8*)&ldsA[(mbase + i * 16 + lrow) * 32 + quad * 8];
#pragma unroll
    for (int i = 0; i < 4; ++i)
      bfr[i] = *(const bf16x8*)&ldsB[(nbase + i * 16 + lrow) * 32 + quad * 8];
#pragma unroll
    for (int mi = 0; mi < 4; ++mi)
#pragma unroll
      for (int ni = 0; ni < 4; ++ni)
        acc[mi][ni] = __builtin_amdgcn_mfma_f32_16x16x32_bf16(af[mi], bfr[ni],
                                                              acc[mi][ni], 0, 0, 0);
  };

  if (MODE == 0) {
    for (int kb = 0; kb < K / 32; ++kb) k_step(kb);
  } else {
    for (int e = 0; e < 4; ++e) {
      if (!(tm & (1 << e))) continue;  // wave-uniform: skip inactive expert's K range
      for (int kb = e * 64; kb < e * 64 + 64; ++kb) k_step(kb);
    }
  }

  // epilogue: C/D layout col = lane&15, row = quad*4 + reg  [m89/m91 verified]
  if (MODE == 0) {
    __bf16* out = (__bf16*)outp;
#pragma unroll
    for (int mi = 0; mi < 4; ++mi) {
#pragma unroll
      for (int ni = 0; ni < 4; ++ni) {
        int gcol = bx * 128 + nbase + ni * 16 + lrow;
        int e = gcol >> 11;
        int h = gcol & 2047;
        float b = bias[e * 2048 + h];
        f32x4 v = acc[mi][ni];
#pragma unroll
        for (int r = 0; r < 4; ++r) {
          int row = by * 128 + mbase + mi * 16 + quad * 4 + r;
          float xv = v[r] + b;
          float gl = 0.5f * xv * (1.0f + erff(xv * 0.70710678118654752440f));
          out[(size_t)row * 8192 + gcol] = (__bf16)(gl * cc[row * 4 + e]);
        }
      }
    }
  } else {
    float* out = (float*)outp;
    float bb[4][4];
#pragma unroll
    for (int ni = 0; ni < 4; ++ni) {
      int gcol = bx * 128 + nbase + ni * 16 + lrow;
#pragma unroll
      for (int e = 0; e < 4; ++e) bb[ni][e] = bias[e * 2048 + gcol];
    }
#pragma unroll
    for (int mi = 0; mi < 4; ++mi) {
#pragma unroll
      for (int r = 0; r < 4; ++r) {
        int row = by * 128 + mbase + mi * 16 + quad * 4 + r;
        int tok = permc[row];
        const float* cw = cc + (size_t)row * 4;
        float c0 = cw[0], c1 = cw[1], c2 = cw[2], c3 = cw[3];
#pragma unroll
        for (int ni = 0; ni < 4; ++ni) {
          int gcol = bx * 128 + nbase + ni * 16 + lrow;
          float s = acc[mi][ni][r] + c0 * bb[ni][0] + c1 * bb[ni][1] +
                    c2 * bb[ni][2] + c3 * bb[ni][3];
          out[(size_t)tok * 2048 + gcol] = s;
        }
      }
    }
  }
}

// ---------------------------------------------------------------------------
// launch
// ---------------------------------------------------------------------------
extern "C" void kernel_launch(void* const* d_in, const int* in_sizes, int n_in,
                              void* d_out, int out_size, void* d_ws, size_t ws_size,
                              hipStream_t stream) {
  const float* hs = (const float*)d_in[0];      // [8,2048,2048]
  const float* gate_w = (const float*)d_in[1];  // [4,2048]
  const float* w1 = (const float*)d_in[2];      // [4,2048,2048]
  const float* b1 = (const float*)d_in[3];      // [4,2048]
  const float* w2 = (const float*)d_in[4];      // [4,2048,2048]
  const float* b2 = (const float*)d_in[5];      // [4,2048]
  float* out = (float*)d_out;

  const int N = 16384, D = 2048, H = 2048, E = 4;
  const int CHUNK = 4096;

  char* p = (char*)d_ws;
  __bf16* xb = (__bf16*)p;    p += (size_t)N * D * 2;      //  64 MiB (token-order bf16)
  __bf16* w1t = (__bf16*)p;   p += (size_t)E * D * H * 2;  //  32 MiB  [e][h][d]
  __bf16* w2t = (__bf16*)p;   p += (size_t)E * H * H * 2;  //  32 MiB  [o][e*2048+h]
  float* comb = (float*)p;    p += (size_t)N * 4 * 4;      // 256 KiB (token order)
  float* comb_s = (float*)p;  p += (size_t)N * 4 * 4;      // 256 KiB (sorted)
  int* perm = (int*)p;        p += (size_t)N * 4;          //  64 KiB
  int* pairid = (int*)p;      p += (size_t)N * 4;          //  64 KiB
  int* pm_s = (int*)p;        p += (size_t)N * 4;          //  64 KiB
  int* meta = (int*)p;        p += 32 * 4;                 // cnt[8], cur[8], off[8]
  int* tmask = (int*)p;       p += 128 * 4;                // N/128 tiles
  __bf16* h1s = (__bf16*)p;                                //  64 MiB [CHUNK][E*H]

  hipMemsetAsync(meta, 0, 64, stream);  // zero cnt[8] + cur[8]
  transpose_cvt<2048, true><<<dim3(64, 64, 4), 256, 0, stream>>>(w1, w1t);
  transpose_cvt<8192, false><<<dim3(64, 64, 4), 256, 0, stream>>>(w2, w2t);
  router_fused<<<dim3(N / 16), 256, 0, stream>>>((const float4*)hs,
                                                 (const float4*)gate_w,
                                                 (bf16x4*)xb, comb, pairid, meta);
  scan6<<<1, 1, 0, stream>>>(meta, meta + 16);
  assign_kernel<<<dim3(N / 256), 256, 0, stream>>>(pairid, (const float4*)comb,
                                                   meta + 16, meta + 8, perm,
                                                   (float4*)comb_s, pm_s);
  tile_mask_kernel<<<1, 128, 0, stream>>>(pm_s, tmask);

  for (int c = 0; c < N / CHUNK; ++c) {
    const float* cc = comb_s + (size_t)c * CHUNK * 4;
    const int* tmc = tmask + c * (CHUNK / 128);
    gemm_bt<0><<<dim3(E * H / 128, CHUNK / 128), 256, 0, stream>>>(
        xb, w1t, b1, cc, tmc, perm + c * CHUNK, h1s);
    gemm_bt<1><<<dim3(H / 128, CHUNK / 128), 256, 0, stream>>>(h1s, w2t, b2, cc, tmc,
                                                               perm + c * CHUNK, out);
  }
}

// Round 2
// 1456.318 us; speedup vs baseline: 1.1657x; 1.1299x over previous
//
#include <hip/hip_runtime.h>
#include <hip/hip_bf16.h>
#include <math.h>

typedef __bf16 bf16x8 __attribute__((ext_vector_type(8)));
typedef __bf16 bf16x4 __attribute__((ext_vector_type(4)));
typedef float f32x4 __attribute__((ext_vector_type(4)));

typedef __attribute__((address_space(1))) void GV;
typedef __attribute__((address_space(3))) void LV;

// ---------------------------------------------------------------------------
// transpose_cvt<OSTRIDE, EBLOCK>: per-expert [R=2048][C=2048] fp32 -> bf16 ^T
//   EBLOCK=true : out[e][c][r]                 OSTRIDE=2048   (w1t for GEMM1)
//   EBLOCK=false: out[c*OSTRIDE + e*2048 + r]  OSTRIDE=8192   (w2t for GEMM2)
// ---------------------------------------------------------------------------
template <int OSTRIDE, bool EBLOCK>
__global__ __launch_bounds__(256) void transpose_cvt(const float* __restrict__ in,
                                                     __bf16* __restrict__ out) {
  __shared__ float tile[32][33];
  const int e = blockIdx.z;
  const size_t ibase = (size_t)e * 2048 * 2048;
  const size_t obase = EBLOCK ? (size_t)e * 2048 * 2048 : (size_t)e * 2048;
  int c0 = blockIdx.x * 32, r0 = blockIdx.y * 32;
  int tx = threadIdx.x & 31, ty = threadIdx.x >> 5;
#pragma unroll
  for (int i = 0; i < 32; i += 8)
    tile[ty + i][tx] = in[ibase + (size_t)(r0 + ty + i) * 2048 + c0 + tx];
  __syncthreads();
#pragma unroll
  for (int i = 0; i < 32; i += 8)
    out[obase + (size_t)(c0 + ty + i) * OSTRIDE + r0 + tx] = (__bf16)tile[tx][ty + i];
}

// ---------------------------------------------------------------------------
// router_fused v3: 2 tokens per WAVE (8/block, grid N/8), all 16 x-loads
// batched into registers before use (latency hiding), gw staged in LDS,
// butterfly reduce so lanes 0/1 run the two softmaxes concurrently.
// Fused fp32->bf16 conversion of the token row (written in TOKEN order).
// ---------------------------------------------------------------------------
__global__ __launch_bounds__(256) void router_fused(const float4* __restrict__ hs4,
                                                    const float4* __restrict__ gw4,
                                                    bf16x4* __restrict__ xb,
                                                    float* __restrict__ comb,
                                                    int* __restrict__ pairid,
                                                    int* __restrict__ cnt) {
  __shared__ float4 gwS[4 * 512];  // 32 KiB: gw[e][d] as float4
  const int tid = threadIdx.x;
  for (int j = tid; j < 2048; j += 256) gwS[j] = gw4[j];
  __syncthreads();

  const int lane = tid & 63;
  const int wv = tid >> 6;
  const int nA = blockIdx.x * 8 + wv * 2;
  const int nB = nA + 1;

  const float4* xA = hs4 + (size_t)nA * 512;
  const float4* xB = hs4 + (size_t)nB * 512;
  bf16x4* dA = xb + (size_t)nA * 512;
  bf16x4* dB = xb + (size_t)nB * 512;

  // issue all 16 global loads back-to-back: 16 KB in flight per wave
  float4 va[8], vb[8];
#pragma unroll
  for (int i = 0; i < 8; ++i) va[i] = xA[i * 64 + lane];
#pragma unroll
  for (int i = 0; i < 8; ++i) vb[i] = xB[i * 64 + lane];

  float a0 = 0.f, a1 = 0.f, a2 = 0.f, a3 = 0.f;
  float c0 = 0.f, c1 = 0.f, c2 = 0.f, c3 = 0.f;
#pragma unroll
  for (int i = 0; i < 8; ++i) {
    int j = i * 64 + lane;
    float4 g0 = gwS[j], g1 = gwS[512 + j], g2 = gwS[1024 + j], g3 = gwS[1536 + j];
    float4 v = va[i];
    a0 += v.x * g0.x + v.y * g0.y + v.z * g0.z + v.w * g0.w;
    a1 += v.x * g1.x + v.y * g1.y + v.z * g1.z + v.w * g1.w;
    a2 += v.x * g2.x + v.y * g2.y + v.z * g2.z + v.w * g2.w;
    a3 += v.x * g3.x + v.y * g3.y + v.z * g3.z + v.w * g3.w;
    bf16x4 oa;
    oa.x = (__bf16)v.x; oa.y = (__bf16)v.y; oa.z = (__bf16)v.z; oa.w = (__bf16)v.w;
    dA[j] = oa;
    float4 w = vb[i];
    c0 += w.x * g0.x + w.y * g0.y + w.z * g0.z + w.w * g0.w;
    c1 += w.x * g1.x + w.y * g1.y + w.z * g1.z + w.w * g1.w;
    c2 += w.x * g2.x + w.y * g2.y + w.z * g2.z + w.w * g2.w;
    c3 += w.x * g3.x + w.y * g3.y + w.z * g3.z + w.w * g3.w;
    bf16x4 ob;
    ob.x = (__bf16)w.x; ob.y = (__bf16)w.y; ob.z = (__bf16)w.z; ob.w = (__bf16)w.w;
    dB[j] = ob;
  }

  // butterfly: every lane ends with the full sums for both tokens
#pragma unroll
  for (int off = 32; off > 0; off >>= 1) {
    a0 += __shfl_xor(a0, off); a1 += __shfl_xor(a1, off);
    a2 += __shfl_xor(a2, off); a3 += __shfl_xor(a3, off);
    c0 += __shfl_xor(c0, off); c1 += __shfl_xor(c1, off);
    c2 += __shfl_xor(c2, off); c3 += __shfl_xor(c3, off);
  }

  if (lane < 2) {  // lane 0 -> token A, lane 1 -> token B (same code path)
    const int n = lane ? nB : nA;
    float l[4];
    l[0] = lane ? c0 : a0; l[1] = lane ? c1 : a1;
    l[2] = lane ? c2 : a2; l[3] = lane ? c3 : a3;
    float m = fmaxf(fmaxf(l[0], l[1]), fmaxf(l[2], l[3]));
    float p[4], sum = 0.f;
#pragma unroll
    for (int e = 0; e < 4; ++e) { p[e] = expf(l[e] - m); sum += p[e]; }
#pragma unroll
    for (int e = 0; e < 4; ++e) p[e] /= sum;
    int i1 = 0;
#pragma unroll
    for (int e = 1; e < 4; ++e) if (p[e] > p[i1]) i1 = e;
    int i2 = -1;
#pragma unroll
    for (int e = 0; e < 4; ++e) {
      if (e == i1) continue;
      if (i2 < 0 || p[e] > p[i2]) i2 = e;
    }
    float ws = p[i1] + p[i2];
#pragma unroll
    for (int e = 0; e < 4; ++e)
      comb[(size_t)n * 4 + e] = (e == i1 || e == i2) ? p[e] / ws : 0.f;
    int a = min(i1, i2), b = max(i1, i2);
    int pid = (a == 0) ? (b - 1) : ((a == 1) ? (1 + b) : (2 + b));
    pairid[n] = pid;
    atomicAdd(&cnt[pid], 1);
  }
}

// exclusive scan over 6 bucket counts (1 thread)
__global__ void scan6(const int* __restrict__ cnt, int* __restrict__ off) {
  int o = 0;
  for (int i = 0; i < 6; ++i) { off[i] = o; o += cnt[i]; }
}

// assign sorted positions; gather combine weights + pair bitmask into sorted order
__global__ __launch_bounds__(256) void assign_kernel(const int* __restrict__ pairid,
                                                     const float4* __restrict__ comb4,
                                                     const int* __restrict__ off,
                                                     int* __restrict__ cur,
                                                     int* __restrict__ perm,
                                                     float4* __restrict__ comb_s,
                                                     int* __restrict__ pm_s) {
  int n = blockIdx.x * 256 + threadIdx.x;
  int pid = pairid[n];
  int pos = off[pid] + atomicAdd(&cur[pid], 1);
  perm[pos] = n;
  comb_s[pos] = comb4[n];
  // pair -> expert bitmask: (0,1)(0,2)(0,3)(1,2)(1,3)(2,3)
  const int lut[6] = {3, 5, 9, 6, 10, 12};
  pm_s[pos] = lut[pid];
}

// per-128-row-tile active-expert mask (OR of token pair-masks)
__global__ void tile_mask_kernel(const int* __restrict__ pm_s, int* __restrict__ tmask) {
  int t = threadIdx.x;  // 128 tiles, 1 block of 128 threads
  int m = 0;
  for (int i = 0; i < 128; ++i) m |= pm_s[t * 128 + i];
  tmask[t] = m;
}

// ---------------------------------------------------------------------------
// gemm_bt<MODE>: C = A[M,K] @ Bt[Nout,K]^T, 128x128 tile, BK=32,
// mfma_f32_16x16x32_bf16, global_load_lds width-16 staging (m97 structure).
// MODE 0: GEMM1 K=2048, Nout=8192. A = token-order xb, rows gathered via
//         permc (global src of global_load_lds is per-lane). Block exits if
//         its expert (bx>>4) inactive; epilogue +b1, gelu, *combine.
// MODE 1: GEMM2 K=8192, Nout=2048: K-loop visits only active experts' ranges;
//         epilogue + sum_e comb*b2, scatter rows via perm.
// ---------------------------------------------------------------------------
template <int MODE>
__global__ __launch_bounds__(256) void gemm_bt(const __bf16* __restrict__ A,
                                               const __bf16* __restrict__ Bt,
                                               const float* __restrict__ bias,
                                               const float* __restrict__ cc,
                                               const int* __restrict__ tmask,
                                               const int* __restrict__ permc,
                                               void* __restrict__ outp) {
  constexpr int K = (MODE == 0) ? 2048 : 8192;
  __shared__ __bf16 ldsA[128 * 32];
  __shared__ __bf16 ldsB[128 * 32];

  const int tid = threadIdx.x;
  const int lane = tid & 63;
  const int wv = tid >> 6;
  const int bx = blockIdx.x, by = blockIdx.y;

  const int tm = tmask[by];
  if (MODE == 0) {
    if (!(tm & (1 << (bx >> 4)))) return;  // expert inactive for this row-tile
  }

  const int lrow = lane & 15;   // A-row / B-col within 16x16 tile
  const int quad = lane >> 4;   // k-group: k = quad*8 + j
  const int mbase = (wv >> 1) * 64;
  const int nbase = (wv & 1) * 64;

  // hoisted per-thread staging bases; MODE 0 gathers token rows through permc
  size_t aoff[2], boff[2];
#pragma unroll
  for (int t = 0; t < 2; ++t) {
    int g = t * 256 + wv * 64 + lane;  // 16B-chunk id, 0..511
    int row = g >> 2, kc = g & 3;
    int arow = by * 128 + row;
    if (MODE == 0) arow = permc[arow];
    aoff[t] = (size_t)arow * K + kc * 8;
    boff[t] = (size_t)(bx * 128 + row) * K + kc * 8;
  }

  f32x4 acc[4][4] = {};

  auto k_step = [&](int kb) {
    __syncthreads();  // protect LDS from previous iteration's readers
#pragma unroll
    for (int t = 0; t < 2; ++t) {
      const __bf16* ga = A + aoff[t] + (size_t)kb * 32;
      const __bf16* gb = Bt + boff[t] + (size_t)kb * 32;
      int loff = t * 2048 + wv * 512;  // wave-uniform LDS base; HW adds lane*16B
      __builtin_amdgcn_global_load_lds((GV*)ga, (LV*)&ldsA[loff], 16, 0, 0);
      __builtin_amdgcn_global_load_lds((GV*)gb, (LV*)&ldsB[loff], 16, 0, 0);
    }
    __syncthreads();

    bf16x8 af[4], bfr[4];
#pragma unroll
    for (int i = 0; i < 4; ++i)
      af[i] = *(const bf16x8*)&ldsA[(mbase + i * 16 + lrow) * 32 + quad * 8];
#pragma unroll
    for (int i = 0; i < 4; ++i)
      bfr[i] = *(const bf16x8*)&ldsB[(nbase + i * 16 + lrow) * 32 + quad * 8];
#pragma unroll
    for (int mi = 0; mi < 4; ++mi)
#pragma unroll
      for (int ni = 0; ni < 4; ++ni)
        acc[mi][ni] = __builtin_amdgcn_mfma_f32_16x16x32_bf16(af[mi], bfr[ni],
                                                              acc[mi][ni], 0, 0, 0);
  };

  if (MODE == 0) {
    for (int kb = 0; kb < K / 32; ++kb) k_step(kb);
  } else {
    for (int e = 0; e < 4; ++e) {
      if (!(tm & (1 << e))) continue;  // wave-uniform: skip inactive expert's K range
      for (int kb = e * 64; kb < e * 64 + 64; ++kb) k_step(kb);
    }
  }

  // epilogue: C/D layout col = lane&15, row = quad*4 + reg  [m89/m91 verified]
  if (MODE == 0) {
    __bf16* out = (__bf16*)outp;
#pragma unroll
    for (int mi = 0; mi < 4; ++mi) {
#pragma unroll
      for (int ni = 0; ni < 4; ++ni) {
        int gcol = bx * 128 + nbase + ni * 16 + lrow;
        int e = gcol >> 11;
        int h = gcol & 2047;
        float b = bias[e * 2048 + h];
        f32x4 v = acc[mi][ni];
#pragma unroll
        for (int r = 0; r < 4; ++r) {
          int row = by * 128 + mbase + mi * 16 + quad * 4 + r;
          float xv = v[r] + b;
          float gl = 0.5f * xv * (1.0f + erff(xv * 0.70710678118654752440f));
          out[(size_t)row * 8192 + gcol] = (__bf16)(gl * cc[row * 4 + e]);
        }
      }
    }
  } else {
    float* out = (float*)outp;
    float bb[4][4];
#pragma unroll
    for (int ni = 0; ni < 4; ++ni) {
      int gcol = bx * 128 + nbase + ni * 16 + lrow;
#pragma unroll
      for (int e = 0; e < 4; ++e) bb[ni][e] = bias[e * 2048 + gcol];
    }
#pragma unroll
    for (int mi = 0; mi < 4; ++mi) {
#pragma unroll
      for (int r = 0; r < 4; ++r) {
        int row = by * 128 + mbase + mi * 16 + quad * 4 + r;
        int tok = permc[row];
        const float* cw = cc + (size_t)row * 4;
        float c0 = cw[0], c1 = cw[1], c2 = cw[2], c3 = cw[3];
#pragma unroll
        for (int ni = 0; ni < 4; ++ni) {
          int gcol = bx * 128 + nbase + ni * 16 + lrow;
          float s = acc[mi][ni][r] + c0 * bb[ni][0] + c1 * bb[ni][1] +
                    c2 * bb[ni][2] + c3 * bb[ni][3];
          out[(size_t)tok * 2048 + gcol] = s;
        }
      }
    }
  }
}

// ---------------------------------------------------------------------------
// launch
// ---------------------------------------------------------------------------
extern "C" void kernel_launch(void* const* d_in, const int* in_sizes, int n_in,
                              void* d_out, int out_size, void* d_ws, size_t ws_size,
                              hipStream_t stream) {
  const float* hs = (const float*)d_in[0];      // [8,2048,2048]
  const float* gate_w = (const float*)d_in[1];  // [4,2048]
  const float* w1 = (const float*)d_in[2];      // [4,2048,2048]
  const float* b1 = (const float*)d_in[3];      // [4,2048]
  const float* w2 = (const float*)d_in[4];      // [4,2048,2048]
  const float* b2 = (const float*)d_in[5];      // [4,2048]
  float* out = (float*)d_out;

  const int N = 16384, D = 2048, H = 2048, E = 4;

  char* p = (char*)d_ws;
  __bf16* xb = (__bf16*)p;    p += (size_t)N * D * 2;      //  64 MiB (token-order bf16)
  __bf16* w1t = (__bf16*)p;   p += (size_t)E * D * H * 2;  //  32 MiB  [e][h][d]
  __bf16* w2t = (__bf16*)p;   p += (size_t)E * H * H * 2;  //  32 MiB  [o][e*2048+h]
  float* comb = (float*)p;    p += (size_t)N * 4 * 4;      // 256 KiB (token order)
  float* comb_s = (float*)p;  p += (size_t)N * 4 * 4;      // 256 KiB (sorted)
  int* perm = (int*)p;        p += (size_t)N * 4;          //  64 KiB
  int* pairid = (int*)p;      p += (size_t)N * 4;          //  64 KiB
  int* pm_s = (int*)p;        p += (size_t)N * 4;          //  64 KiB
  int* meta = (int*)p;        p += 32 * 4;                 // cnt[8], cur[8], off[8]
  int* tmask = (int*)p;       p += 128 * 4;                // N/128 tiles
  __bf16* h1s = (__bf16*)p;                                // [CHUNK][E*H]

  // pick the largest CHUNK whose h1s fits the remaining workspace:
  // fewer serial dispatches -> fewer tails, 4x GEMM2 occupancy.
  size_t used = (size_t)(p - (char*)d_ws);
  int CHUNK = 4096;
  if (ws_size >= used + (size_t)16384 * 8192 * 2) CHUNK = 16384;
  else if (ws_size >= used + (size_t)8192 * 8192 * 2) CHUNK = 8192;

  hipMemsetAsync(meta, 0, 64, stream);  // zero cnt[8] + cur[8]
  transpose_cvt<2048, true><<<dim3(64, 64, 4), 256, 0, stream>>>(w1, w1t);
  transpose_cvt<8192, false><<<dim3(64, 64, 4), 256, 0, stream>>>(w2, w2t);
  router_fused<<<dim3(N / 8), 256, 0, stream>>>((const float4*)hs,
                                                (const float4*)gate_w,
                                                (bf16x4*)xb, comb, pairid, meta);
  scan6<<<1, 1, 0, stream>>>(meta, meta + 16);
  assign_kernel<<<dim3(N / 256), 256, 0, stream>>>(pairid, (const float4*)comb,
                                                   meta + 16, meta + 8, perm,
                                                   (float4*)comb_s, pm_s);
  tile_mask_kernel<<<1, 128, 0, stream>>>(pm_s, tmask);

  for (int c = 0; c < N / CHUNK; ++c) {
    const float* cc = comb_s + (size_t)c * CHUNK * 4;
    const int* tmc = tmask + c * (CHUNK / 128);
    gemm_bt<0><<<dim3(E * H / 128, CHUNK / 128), 256, 0, stream>>>(
        xb, w1t, b1, cc, tmc, perm + c * CHUNK, h1s);
    gemm_bt<1><<<dim3(H / 128, CHUNK / 128), 256, 0, stream>>>(h1s, w2t, b2, cc, tmc,
                                                               perm + c * CHUNK, out);
  }
}

// Round 3
// 1440.611 us; speedup vs baseline: 1.1784x; 1.0109x over previous
//
#include <hip/hip_runtime.h>
#include <hip/hip_bf16.h>
#include <math.h>

typedef __bf16 bf16x8 __attribute__((ext_vector_type(8)));
typedef __bf16 bf16x4 __attribute__((ext_vector_type(4)));
typedef float f32x4 __attribute__((ext_vector_type(4)));

typedef __attribute__((address_space(1))) void GV;
typedef __attribute__((address_space(3))) void LV;

// ---------------------------------------------------------------------------
// transpose_cvt<OSTRIDE, EBLOCK>: per-expert [R=2048][C=2048] fp32 -> bf16 ^T
//   EBLOCK=true : out[e][c][r]                 OSTRIDE=2048   (w1t for GEMM1)
//   EBLOCK=false: out[c*OSTRIDE + e*2048 + r]  OSTRIDE=8192   (w2t for GEMM2)
// ---------------------------------------------------------------------------
template <int OSTRIDE, bool EBLOCK>
__global__ __launch_bounds__(256) void transpose_cvt(const float* __restrict__ in,
                                                     __bf16* __restrict__ out) {
  __shared__ float tile[32][33];
  const int e = blockIdx.z;
  const size_t ibase = (size_t)e * 2048 * 2048;
  const size_t obase = EBLOCK ? (size_t)e * 2048 * 2048 : (size_t)e * 2048;
  int c0 = blockIdx.x * 32, r0 = blockIdx.y * 32;
  int tx = threadIdx.x & 31, ty = threadIdx.x >> 5;
#pragma unroll
  for (int i = 0; i < 32; i += 8)
    tile[ty + i][tx] = in[ibase + (size_t)(r0 + ty + i) * 2048 + c0 + tx];
  __syncthreads();
#pragma unroll
  for (int i = 0; i < 32; i += 8)
    out[obase + (size_t)(c0 + ty + i) * OSTRIDE + r0 + tx] = (__bf16)tile[tx][ty + i];
}

// ---------------------------------------------------------------------------
// router_fused: 2 tokens/wave, batched loads, gw in LDS, butterfly reduce,
// fused fp32->bf16 conversion of token rows (token order).
// ---------------------------------------------------------------------------
__global__ __launch_bounds__(256) void router_fused(const float4* __restrict__ hs4,
                                                    const float4* __restrict__ gw4,
                                                    bf16x4* __restrict__ xb,
                                                    float* __restrict__ comb,
                                                    int* __restrict__ pairid,
                                                    int* __restrict__ cnt) {
  __shared__ float4 gwS[4 * 512];  // 32 KiB: gw[e][d] as float4
  const int tid = threadIdx.x;
  for (int j = tid; j < 2048; j += 256) gwS[j] = gw4[j];
  __syncthreads();

  const int lane = tid & 63;
  const int wv = tid >> 6;
  const int nA = blockIdx.x * 8 + wv * 2;
  const int nB = nA + 1;

  const float4* xA = hs4 + (size_t)nA * 512;
  const float4* xB = hs4 + (size_t)nB * 512;
  bf16x4* dA = xb + (size_t)nA * 512;
  bf16x4* dB = xb + (size_t)nB * 512;

  float4 va[8], vb[8];
#pragma unroll
  for (int i = 0; i < 8; ++i) va[i] = xA[i * 64 + lane];
#pragma unroll
  for (int i = 0; i < 8; ++i) vb[i] = xB[i * 64 + lane];

  float a0 = 0.f, a1 = 0.f, a2 = 0.f, a3 = 0.f;
  float c0 = 0.f, c1 = 0.f, c2 = 0.f, c3 = 0.f;
#pragma unroll
  for (int i = 0; i < 8; ++i) {
    int j = i * 64 + lane;
    float4 g0 = gwS[j], g1 = gwS[512 + j], g2 = gwS[1024 + j], g3 = gwS[1536 + j];
    float4 v = va[i];
    a0 += v.x * g0.x + v.y * g0.y + v.z * g0.z + v.w * g0.w;
    a1 += v.x * g1.x + v.y * g1.y + v.z * g1.z + v.w * g1.w;
    a2 += v.x * g2.x + v.y * g2.y + v.z * g2.z + v.w * g2.w;
    a3 += v.x * g3.x + v.y * g3.y + v.z * g3.z + v.w * g3.w;
    bf16x4 oa;
    oa.x = (__bf16)v.x; oa.y = (__bf16)v.y; oa.z = (__bf16)v.z; oa.w = (__bf16)v.w;
    dA[j] = oa;
    float4 w = vb[i];
    c0 += w.x * g0.x + w.y * g0.y + w.z * g0.z + w.w * g0.w;
    c1 += w.x * g1.x + w.y * g1.y + w.z * g1.z + w.w * g1.w;
    c2 += w.x * g2.x + w.y * g2.y + w.z * g2.z + w.w * g2.w;
    c3 += w.x * g3.x + w.y * g3.y + w.z * g3.z + w.w * g3.w;
    bf16x4 ob;
    ob.x = (__bf16)w.x; ob.y = (__bf16)w.y; ob.z = (__bf16)w.z; ob.w = (__bf16)w.w;
    dB[j] = ob;
  }

#pragma unroll
  for (int off = 32; off > 0; off >>= 1) {
    a0 += __shfl_xor(a0, off); a1 += __shfl_xor(a1, off);
    a2 += __shfl_xor(a2, off); a3 += __shfl_xor(a3, off);
    c0 += __shfl_xor(c0, off); c1 += __shfl_xor(c1, off);
    c2 += __shfl_xor(c2, off); c3 += __shfl_xor(c3, off);
  }

  if (lane < 2) {
    const int n = lane ? nB : nA;
    float l[4];
    l[0] = lane ? c0 : a0; l[1] = lane ? c1 : a1;
    l[2] = lane ? c2 : a2; l[3] = lane ? c3 : a3;
    float m = fmaxf(fmaxf(l[0], l[1]), fmaxf(l[2], l[3]));
    float p[4], sum = 0.f;
#pragma unroll
    for (int e = 0; e < 4; ++e) { p[e] = expf(l[e] - m); sum += p[e]; }
#pragma unroll
    for (int e = 0; e < 4; ++e) p[e] /= sum;
    int i1 = 0;
#pragma unroll
    for (int e = 1; e < 4; ++e) if (p[e] > p[i1]) i1 = e;
    int i2 = -1;
#pragma unroll
    for (int e = 0; e < 4; ++e) {
      if (e == i1) continue;
      if (i2 < 0 || p[e] > p[i2]) i2 = e;
    }
    float ws = p[i1] + p[i2];
#pragma unroll
    for (int e = 0; e < 4; ++e)
      comb[(size_t)n * 4 + e] = (e == i1 || e == i2) ? p[e] / ws : 0.f;
    int a = min(i1, i2), b = max(i1, i2);
    int pid = (a == 0) ? (b - 1) : ((a == 1) ? (1 + b) : (2 + b));
    pairid[n] = pid;
    atomicAdd(&cnt[pid], 1);
  }
}

// exclusive scan over 6 bucket counts (1 thread)
__global__ void scan6(const int* __restrict__ cnt, int* __restrict__ off) {
  int o = 0;
  for (int i = 0; i < 6; ++i) { off[i] = o; o += cnt[i]; }
}

// assign sorted positions; gather combine weights + pair bitmask into sorted order
__global__ __launch_bounds__(256) void assign_kernel(const int* __restrict__ pairid,
                                                     const float4* __restrict__ comb4,
                                                     const int* __restrict__ off,
                                                     int* __restrict__ cur,
                                                     int* __restrict__ perm,
                                                     float4* __restrict__ comb_s,
                                                     int* __restrict__ pm_s) {
  int n = blockIdx.x * 256 + threadIdx.x;
  int pid = pairid[n];
  int pos = off[pid] + atomicAdd(&cur[pid], 1);
  perm[pos] = n;
  comb_s[pos] = comb4[n];
  // pair -> expert bitmask: (0,1)(0,2)(0,3)(1,2)(1,3)(2,3)
  const int lut[6] = {3, 5, 9, 6, 10, 12};
  pm_s[pos] = lut[pid];
}

// per-256-row-tile active-expert mask (OR of token pair-masks)
__global__ void tile_mask_kernel(const int* __restrict__ pm_s, int* __restrict__ tmask) {
  int t = threadIdx.x;  // 64 tiles, 1 block of 64 threads
  int m = 0;
  for (int i = 0; i < 256; ++i) m |= pm_s[t * 256 + i];
  tmask[t] = m;
}

// ---------------------------------------------------------------------------
// gemm256<MODE>: 256x256 tile, BK=64, 8 waves (2Mx4N), 128 KiB dbuf LDS,
// 4-phase schedule w/ counted-latency staging (T3+T4), XOR LDS swizzle (T2),
// setprio around MFMA (T5). mfma_f32_16x16x32_bf16.
//   LDS swizzle: logical 16B-chunk (row, cc) stored at slot cc^(row&7);
//   global_load_lds keeps linear dest + inverse-swizzled per-lane source.
// MODE 0: GEMM1 K=2048, Nout=8192, A-rows gathered via permc; epilogue
//         +b1, gelu, *combine -> h1s bf16. Early-exit on inactive expert.
// MODE 1: GEMM2 K=8192, Nout=2048, K-loop visits only active experts'
//         64-col tiles; epilogue + sum_e comb*b2, scatter rows via perm.
// ---------------------------------------------------------------------------
template <int MODE>
__global__ __launch_bounds__(512) void gemm256(const __bf16* __restrict__ A,
                                               const __bf16* __restrict__ Bt,
                                               const float* __restrict__ bias,
                                               const float* __restrict__ cc,
                                               const int* __restrict__ tmask,
                                               const int* __restrict__ permc,
                                               void* __restrict__ outp) {
  constexpr int K = (MODE == 0) ? 2048 : 8192;
  // A: buf b at b*16384 bf16; B: 32768 + b*16384. total 128 KiB.
  __shared__ __attribute__((aligned(128))) __bf16 lds[65536];

  const int tid = threadIdx.x;
  const int lane = tid & 63, wv = tid >> 6;
  const int wm = wv >> 2, wn = wv & 3;        // 2M x 4N wave grid
  const int lrow = lane & 15, quad = lane >> 4;
  const int bx = blockIdx.x, by = blockIdx.y;

  const int tm = tmask[by];
  if (MODE == 0 && !(tm & (1 << (bx >> 3)))) return;

  // active K-tile list: MODE1 packs active expert ids into aep (8b each)
  int nt, aep = 0;
  if (MODE == 0) {
    nt = K / 64;
  } else {
    int na = 0;
    for (int e = 0; e < 4; ++e)
      if (tm & (1 << e)) { aep |= e << (na * 8); ++na; }
    nt = na * 32;
  }
  auto kb_of = [&](int t) -> int {
    return (MODE == 0) ? t : ((aep >> ((t >> 5) * 8)) & 7) * 32 + (t & 31);
  };

  // staging: 2048 chunks (16B) per operand tile; thread covers c = i*512+tid.
  // linear LDS dest; source col-chunk inverse-swizzled: cc = (c&7)^(row&7).
  const __bf16* asrc[4];
  const __bf16* bsrc[4];
  int lofA[4], lofB[4];
#pragma unroll
  for (int i = 0; i < 4; ++i) {
    int c = i * 512 + tid;
    int row = c >> 3, cc8 = (c & 7) ^ (row & 7);
    int arow = by * 256 + row;
    if (MODE == 0) arow = permc[arow];
    asrc[i] = A + (size_t)arow * K + cc8 * 8;
    bsrc[i] = Bt + (size_t)(bx * 256 + row) * K + cc8 * 8;
    lofA[i] = (i * 512 + wv * 64) * 8;          // wave-uniform; HW adds lane*16B
    lofB[i] = 32768 + (i * 512 + wv * 64) * 8;
  }

  auto stageA = [&](int nbuf, int kb) {
#pragma unroll
    for (int i = 0; i < 4; ++i)
      __builtin_amdgcn_global_load_lds((GV*)(asrc[i] + (size_t)kb * 64),
                                       (LV*)&lds[nbuf * 16384 + lofA[i]], 16, 0, 0);
  };
  auto stageB = [&](int nbuf, int kb) {
#pragma unroll
    for (int i = 0; i < 4; ++i)
      __builtin_amdgcn_global_load_lds((GV*)(bsrc[i] + (size_t)kb * 64),
                                       (LV*)&lds[nbuf * 16384 + lofB[i]], 16, 0, 0);
  };

  // frag read: row ≡ lrow (mod 8) -> swizzled slot = (kk*4+quad)^(lrow&7)
  const int aoff = wm * 8192 + lrow * 64;   // (wm*128 + lrow)*64
  const int boff = wn * 4096 + lrow * 64;   // (wn*64 + lrow)*64
  const int sk0 = (quad ^ (lrow & 7)) * 8;
  const int sk1 = ((4 + quad) ^ (lrow & 7)) * 8;

  f32x4 acc[8][4] = {};
  bf16x8 af[4][2];        // A frags of current mh
  bf16x8 bfr[2][2][2];    // B frags [nh][n][kk], both halves persist

#define LDA_FRAGS(MH)                                                          \
  _Pragma("unroll") for (int m = 0; m < 4; ++m) {                              \
    af[m][0] = *(const bf16x8*)&lds[cb16 + aoff + (MH)*4096 + m * 1024 + sk0]; \
    af[m][1] = *(const bf16x8*)&lds[cb16 + aoff + (MH)*4096 + m * 1024 + sk1]; \
  }
#define LDB_FRAGS(NH)                                                          \
  _Pragma("unroll") for (int n = 0; n < 2; ++n) {                              \
    bfr[NH][n][0] =                                                            \
        *(const bf16x8*)&lds[32768 + cb16 + boff + (NH)*2048 + n * 1024 + sk0];\
    bfr[NH][n][1] =                                                            \
        *(const bf16x8*)&lds[32768 + cb16 + boff + (NH)*2048 + n * 1024 + sk1];\
  }
#define BARRIER_LGKM                                                           \
  __builtin_amdgcn_s_barrier();                                                \
  asm volatile("s_waitcnt lgkmcnt(0)" ::: "memory");                           \
  __builtin_amdgcn_sched_barrier(0);
#define MFMA_Q(MH, NH)                                                         \
  __builtin_amdgcn_s_setprio(1);                                               \
  _Pragma("unroll") for (int m = 0; m < 4; ++m)                                \
      _Pragma("unroll") for (int n = 0; n < 2; ++n) {                          \
    acc[(MH)*4 + m][(NH)*2 + n] = __builtin_amdgcn_mfma_f32_16x16x32_bf16(     \
        af[m][0], bfr[NH][n][0], acc[(MH)*4 + m][(NH)*2 + n], 0, 0, 0);        \
    acc[(MH)*4 + m][(NH)*2 + n] = __builtin_amdgcn_mfma_f32_16x16x32_bf16(     \
        af[m][1], bfr[NH][n][1], acc[(MH)*4 + m][(NH)*2 + n], 0, 0, 0);        \
  }                                                                            \
  __builtin_amdgcn_s_setprio(0);

  // prologue: stage tile 0 into buf 0 (one-time full drain)
  {
    int kb0 = kb_of(0);
    stageA(0, kb0);
    stageB(0, kb0);
  }
  asm volatile("s_waitcnt vmcnt(0)" ::: "memory");
  __builtin_amdgcn_s_barrier();

  for (int t = 0; t < nt; ++t) {
    const int cb16 = (t & 1) * 16384;
    const int nbuf = (t & 1) ^ 1;
    const bool more = (t + 1) < nt;
    const int kbn = more ? kb_of(t + 1) : 0;

    // P0: quadrant (0,0); issue next A-tile loads
    LDA_FRAGS(0)
    LDB_FRAGS(0)
    if (more) stageA(nbuf, kbn);
    BARRIER_LGKM
    MFMA_Q(0, 0)
    __builtin_amdgcn_s_barrier();

    // P1: quadrant (0,1); issue next B-tile loads (af persists)
    LDB_FRAGS(1)
    if (more) stageB(nbuf, kbn);
    BARRIER_LGKM
    MFMA_Q(0, 1)
    __builtin_amdgcn_s_barrier();

    // P2: quadrant (1,1); load A(mh=1), bfr[1] persists
    LDA_FRAGS(1)
    BARRIER_LGKM
    MFMA_Q(1, 1)
    __builtin_amdgcn_s_barrier();

    // P3: quadrant (1,0); reuse af(mh=1) + bfr[0]; counted wait lands
    // ~2.5 phases after issue -> HBM latency hidden, never a hot drain.
    BARRIER_LGKM
    MFMA_Q(1, 0)
    asm volatile("s_waitcnt vmcnt(0)" ::: "memory");
    __builtin_amdgcn_s_barrier();
  }

#undef LDA_FRAGS
#undef LDB_FRAGS
#undef BARRIER_LGKM
#undef MFMA_Q

  // epilogue: C/D layout col = lane&15, row = quad*4 + reg  [m89/m91 verified]
  if (MODE == 0) {
    __bf16* out = (__bf16*)outp;
#pragma unroll
    for (int mq = 0; mq < 8; ++mq) {
#pragma unroll
      for (int nq = 0; nq < 4; ++nq) {
        int gcol = bx * 256 + wn * 64 + nq * 16 + lrow;
        int e = gcol >> 11;
        int h = gcol & 2047;
        float b = bias[e * 2048 + h];
        f32x4 v = acc[mq][nq];
#pragma unroll
        for (int r = 0; r < 4; ++r) {
          int row = by * 256 + wm * 128 + mq * 16 + quad * 4 + r;
          float xv = v[r] + b;
          float gl = 0.5f * xv * (1.0f + erff(xv * 0.70710678118654752440f));
          out[(size_t)row * 8192 + gcol] = (__bf16)(gl * cc[row * 4 + e]);
        }
      }
    }
  } else {
    float* out = (float*)outp;
    float bb[4][4];
#pragma unroll
    for (int nq = 0; nq < 4; ++nq) {
      int gcol = bx * 256 + wn * 64 + nq * 16 + lrow;
#pragma unroll
      for (int e = 0; e < 4; ++e) bb[nq][e] = bias[e * 2048 + gcol];
    }
#pragma unroll
    for (int mq = 0; mq < 8; ++mq) {
#pragma unroll
      for (int r = 0; r < 4; ++r) {
        int row = by * 256 + wm * 128 + mq * 16 + quad * 4 + r;
        int tok = permc[row];
        const float* cw = cc + (size_t)row * 4;
        float c0 = cw[0], c1 = cw[1], c2 = cw[2], c3 = cw[3];
#pragma unroll
        for (int nq = 0; nq < 4; ++nq) {
          int gcol = bx * 256 + wn * 64 + nq * 16 + lrow;
          float s = acc[mq][nq][r] + c0 * bb[nq][0] + c1 * bb[nq][1] +
                    c2 * bb[nq][2] + c3 * bb[nq][3];
          out[(size_t)tok * 2048 + gcol] = s;
        }
      }
    }
  }
}

// ---------------------------------------------------------------------------
// launch
// ---------------------------------------------------------------------------
extern "C" void kernel_launch(void* const* d_in, const int* in_sizes, int n_in,
                              void* d_out, int out_size, void* d_ws, size_t ws_size,
                              hipStream_t stream) {
  const float* hs = (const float*)d_in[0];      // [8,2048,2048]
  const float* gate_w = (const float*)d_in[1];  // [4,2048]
  const float* w1 = (const float*)d_in[2];      // [4,2048,2048]
  const float* b1 = (const float*)d_in[3];      // [4,2048]
  const float* w2 = (const float*)d_in[4];      // [4,2048,2048]
  const float* b2 = (const float*)d_in[5];      // [4,2048]
  float* out = (float*)d_out;

  const int N = 16384, D = 2048, H = 2048, E = 4;

  char* p = (char*)d_ws;
  __bf16* xb = (__bf16*)p;    p += (size_t)N * D * 2;      //  64 MiB (token-order bf16)
  __bf16* w1t = (__bf16*)p;   p += (size_t)E * D * H * 2;  //  32 MiB  [e][h][d]
  __bf16* w2t = (__bf16*)p;   p += (size_t)E * H * H * 2;  //  32 MiB  [o][e*2048+h]
  float* comb = (float*)p;    p += (size_t)N * 4 * 4;      // 256 KiB (token order)
  float* comb_s = (float*)p;  p += (size_t)N * 4 * 4;      // 256 KiB (sorted)
  int* perm = (int*)p;        p += (size_t)N * 4;          //  64 KiB
  int* pairid = (int*)p;      p += (size_t)N * 4;          //  64 KiB
  int* pm_s = (int*)p;        p += (size_t)N * 4;          //  64 KiB
  int* meta = (int*)p;        p += 32 * 4;                 // cnt[8], cur[8], off[8]
  int* tmask = (int*)p;       p += 64 * 4;                 // N/256 tiles
  __bf16* h1s = (__bf16*)p;                                // [CHUNK][E*H]

  // largest CHUNK whose h1s fits the remaining workspace
  size_t used = (size_t)(p - (char*)d_ws);
  int CHUNK = 4096;
  if (ws_size >= used + (size_t)16384 * 8192 * 2) CHUNK = 16384;
  else if (ws_size >= used + (size_t)8192 * 8192 * 2) CHUNK = 8192;

  hipMemsetAsync(meta, 0, 64, stream);  // zero cnt[8] + cur[8]
  transpose_cvt<2048, true><<<dim3(64, 64, 4), 256, 0, stream>>>(w1, w1t);
  transpose_cvt<8192, false><<<dim3(64, 64, 4), 256, 0, stream>>>(w2, w2t);
  router_fused<<<dim3(N / 8), 256, 0, stream>>>((const float4*)hs,
                                                (const float4*)gate_w,
                                                (bf16x4*)xb, comb, pairid, meta);
  scan6<<<1, 1, 0, stream>>>(meta, meta + 16);
  assign_kernel<<<dim3(N / 256), 256, 0, stream>>>(pairid, (const float4*)comb,
                                                   meta + 16, meta + 8, perm,
                                                   (float4*)comb_s, pm_s);
  tile_mask_kernel<<<1, 64, 0, stream>>>(pm_s, tmask);

  for (int c = 0; c < N / CHUNK; ++c) {
    const float* cc = comb_s + (size_t)c * CHUNK * 4;
    const int* tmc = tmask + c * (CHUNK / 256);
    gemm256<0><<<dim3(E * H / 256, CHUNK / 256), 512, 0, stream>>>(
        xb, w1t, b1, cc, tmc, perm + c * CHUNK, h1s);
    gemm256<1><<<dim3(H / 256, CHUNK / 256), 512, 0, stream>>>(
        h1s, w2t, b2, cc, tmc, perm + c * CHUNK, out);
  }
}